// Round 4
// baseline (129.331 us; speedup 1.0000x reference)
//
#include <hip/hip_runtime.h>
#include <cmath>

#define N_TOKENS 65536
#define DIM 256
#define NCLUST 128
#define DOUT 256

#define BM 32    // tokens per block
#define BKC 64   // k chunk
#define EPS 2e-3f

typedef __bf16 bf16_t;
typedef bf16_t bf16x8 __attribute__((ext_vector_type(8)));
typedef float f32x4 __attribute__((ext_vector_type(4)));

__device__ inline void split3(float x, bf16_t& h, bf16_t& m, bf16_t& l) {
    h = (bf16_t)x;
    float r = x - (float)h;       // exact
    m = (bf16_t)r;
    float r2 = r - (float)m;      // exact
    l = (bf16_t)r2;
}

// ---------------- kernel 1: precompute (unchanged from round 3) ---------
__global__ __launch_bounds__(256) void precompute_kernel(
    const float* __restrict__ centers,
    const float* __restrict__ proj_w,
    const float* __restrict__ proj_b,
    float* __restrict__ pc,
    float* __restrict__ csq,
    bf16_t* __restrict__ cbh,
    bf16_t* __restrict__ cbm,
    bf16_t* __restrict__ cbl)
{
    __shared__ float cl[DIM];
    __shared__ float red[4];
    const int n = blockIdx.x;
    const int tid = threadIdx.x;

    float cv = centers[n * DIM + tid];
    cl[tid] = cv;

    bf16_t h, m, l;
    split3(cv, h, m, l);
    cbh[(size_t)n * DIM + tid] = h;
    cbm[(size_t)n * DIM + tid] = m;
    cbl[(size_t)n * DIM + tid] = l;

    float s = cv * cv;
    #pragma unroll
    for (int off = 32; off >= 1; off >>= 1)
        s += __shfl_down(s, off, 64);
    if ((tid & 63) == 0) red[tid >> 6] = s;
    __syncthreads();
    if (tid == 0) csq[n] = (red[0] + red[1]) + (red[2] + red[3]);

    float acc = 0.f;
    const float* wrow = proj_w + (size_t)tid * DIM;
    #pragma unroll 4
    for (int d = 0; d < DIM; d += 4) {
        float4 w = *(const float4*)(wrow + d);
        acc = fmaf(w.x, cl[d + 0], acc);
        acc = fmaf(w.y, cl[d + 1], acc);
        acc = fmaf(w.z, cl[d + 2], acc);
        acc = fmaf(w.w, cl[d + 3], acc);
    }
    pc[(size_t)n * DOUT + tid] = acc + proj_b[tid];
}

// ---------------- kernel 2: MFMA scores + filtered argmin + gather ------
__global__ __launch_bounds__(256, 5) void cluster_mfma_kernel(
    const float* __restrict__ x,
    const float* __restrict__ centers,
    const bf16_t* __restrict__ cbh,
    const bf16_t* __restrict__ cbm,
    const bf16_t* __restrict__ cbl,
    const float* __restrict__ csq,
    const float* __restrict__ pc,
    const unsigned char* __restrict__ masks,
    float* __restrict__ out)
{
    __shared__ bf16_t Ah[2][BM * BKC];
    __shared__ bf16_t Am[2][BM * BKC];
    __shared__ bf16_t Al[2][BM * BKC];
    __shared__ float scs[NCLUST];
    __shared__ float sminv[2][BM];
    __shared__ int   smini[2][BM];
    __shared__ float sminT[BM];
    __shared__ int   scnt[BM];
    __shared__ int   sbest[BM];

    const int tid = threadIdx.x;
    const int lane = tid & 63;
    const int wid = tid >> 6;
    const int waveM = wid >> 1;   // token half: waveM*16
    const int waveN = wid & 1;    // cluster half: waveN*64
    const int lr = lane & 15;
    const int lg = lane >> 4;
    const int t0 = blockIdx.x * BM;

    // ---- issue the block's ENTIRE x tile as register prefetch ----
    const int prow = tid >> 3;    // 0..31
    const int pc8 = tid & 7;      // 0..7
    const float* xbase = x + (size_t)(t0 + prow) * DIM + pc8 * 8;
    float4 px[4][2];
    #pragma unroll
    for (int kc = 0; kc < 4; ++kc) {
        px[kc][0] = *(const float4*)(xbase + kc * BKC);
        px[kc][1] = *(const float4*)(xbase + kc * BKC + 4);
    }

    if (tid < NCLUST) scs[tid] = csq[tid];

    const int abase = prow * BKC + ((pc8 ^ (prow & 7)) << 3);

    // convert kc=0 into buffer 0
    {
        float xv[8] = {px[0][0].x, px[0][0].y, px[0][0].z, px[0][0].w,
                       px[0][1].x, px[0][1].y, px[0][1].z, px[0][1].w};
        bf16x8 h8, m8, l8;
        #pragma unroll
        for (int e = 0; e < 8; ++e) {
            bf16_t h, m, l;
            split3(xv[e], h, m, l);
            h8[e] = h; m8[e] = m; l8[e] = l;
        }
        *(bf16x8*)&Ah[0][abase] = h8;
        *(bf16x8*)&Am[0][abase] = m8;
        *(bf16x8*)&Al[0][abase] = l8;
    }
    __syncthreads();

    f32x4 acc[4];
    #pragma unroll
    for (int nr = 0; nr < 4; ++nr)
        acc[nr] = (f32x4){0.f, 0.f, 0.f, 0.f};

    #pragma unroll
    for (int kc = 0; kc < 4; ++kc) {
        const int cur = kc & 1;
        // stage next chunk into the other buffer (no wait needed: regs)
        if (kc < 3) {
            float4 v0 = px[kc + 1][0], v1 = px[kc + 1][1];
            float xv[8] = {v0.x, v0.y, v0.z, v0.w, v1.x, v1.y, v1.z, v1.w};
            bf16x8 h8, m8, l8;
            #pragma unroll
            for (int e = 0; e < 8; ++e) {
                bf16_t h, m, l;
                split3(xv[e], h, m, l);
                h8[e] = h; m8[e] = m; l8[e] = l;
            }
            *(bf16x8*)&Ah[cur ^ 1][abase] = h8;
            *(bf16x8*)&Am[cur ^ 1][abase] = m8;
            *(bf16x8*)&Al[cur ^ 1][abase] = l8;
        }

        #pragma unroll
        for (int ks = 0; ks < 2; ++ks) {
            bf16x8 ah, am, al;
            {
                int r = waveM * 16 + lr;
                int c8r = ks * 4 + lg;
                int idx = r * BKC + ((c8r ^ (r & 7)) << 3);
                ah = *(const bf16x8*)&Ah[cur][idx];
                am = *(const bf16x8*)&Am[cur][idx];
                al = *(const bf16x8*)&Al[cur][idx];
            }
            int koff = kc * BKC + ks * 32 + lg * 8;
            #pragma unroll
            for (int nr = 0; nr < 4; ++nr) {
                int c = waveN * 64 + nr * 16 + lr;
                size_t off = (size_t)c * DIM + koff;
                bf16x8 bh = *(const bf16x8*)(cbh + off);
                bf16x8 bm = *(const bf16x8*)(cbm + off);
                bf16x8 bl = *(const bf16x8*)(cbl + off);
                f32x4 c4 = acc[nr];
                c4 = __builtin_amdgcn_mfma_f32_16x16x32_bf16(al, bh, c4, 0, 0, 0);
                c4 = __builtin_amdgcn_mfma_f32_16x16x32_bf16(ah, bl, c4, 0, 0, 0);
                c4 = __builtin_amdgcn_mfma_f32_16x16x32_bf16(am, bm, c4, 0, 0, 0);
                c4 = __builtin_amdgcn_mfma_f32_16x16x32_bf16(am, bh, c4, 0, 0, 0);
                c4 = __builtin_amdgcn_mfma_f32_16x16x32_bf16(ah, bm, c4, 0, 0, 0);
                c4 = __builtin_amdgcn_mfma_f32_16x16x32_bf16(ah, bh, c4, 0, 0, 0);
                acc[nr] = c4;
            }
        }
        __syncthreads();
    }

    // ---- pass 1: approx argmin (score = csq - 2*dot), per half ----
    // C layout: col(cluster) = lane&15, row(token) = (lane>>4)*4 + reg
    #pragma unroll
    for (int reg = 0; reg < 4; ++reg) {
        float bv = INFINITY;
        int bi = 0;
        #pragma unroll
        for (int nr = 0; nr < 4; ++nr) {
            int c = waveN * 64 + nr * 16 + lr;
            float v = fmaf(-2.f, acc[nr][reg], scs[c]);
            if (v < bv) { bv = v; bi = c; }
        }
        #pragma unroll
        for (int msk = 1; msk < 16; msk <<= 1) {
            float ov = __shfl_xor(bv, msk, 64);
            int oi = __shfl_xor(bi, msk, 64);
            if (ov < bv || (ov == bv && oi < bi)) { bv = ov; bi = oi; }
        }
        if (lr == 0) {
            int t = waveM * 16 + lg * 4 + reg;
            sminv[waveN][t] = bv;
            smini[waveN][t] = bi;
        }
    }
    __syncthreads();
    if (tid < BM) {
        float v0 = sminv[0][tid], v1 = sminv[1][tid];
        sminT[tid] = fminf(v0, v1);
        sbest[tid] = (v1 < v0) ? smini[1][tid] : smini[0][tid];
        scnt[tid] = 0;
    }
    __syncthreads();

    // ---- pass 2: count candidates within EPS of the min ----
    #pragma unroll
    for (int reg = 0; reg < 4; ++reg) {
        int t = waveM * 16 + lg * 4 + reg;
        float thr = sminT[t] + EPS;
        int cnt = 0;
        #pragma unroll
        for (int nr = 0; nr < 4; ++nr) {
            int c = waveN * 64 + nr * 16 + lr;
            float v = fmaf(-2.f, acc[nr][reg], scs[c]);
            cnt += (v <= thr) ? 1 : 0;
        }
        if (cnt > 0) atomicAdd(&scnt[t], cnt);
    }
    __syncthreads();

    // ---- pass 3: exact fp32 recheck for near-tie tokens (rare) ----
    // Bitwise round-1 arithmetic: sequential-k fmaf dot & xsq,
    // d2 = fmaf(-2,dot,xsq) + csq, lexicographic (value,idx) min.
    for (int tt = 0; tt < 8; ++tt) {
        int t = wid * 8 + tt;
        if (scnt[t] < 2) continue;   // wave-uniform
        const float4* xr = (const float4*)(x + (size_t)(t0 + t) * DIM);
        const float4* c0 = (const float4*)(centers + (size_t)(2 * lane) * DIM);
        const float4* c1 = (const float4*)(centers + (size_t)(2 * lane + 1) * DIM);
        float xs = 0.f, d0 = 0.f, d1 = 0.f;
        #pragma unroll 4
        for (int k4 = 0; k4 < 64; ++k4) {
            float4 xv = xr[k4];
            float4 a = c0[k4];
            float4 b = c1[k4];
            xs = fmaf(xv.x, xv.x, xs); d0 = fmaf(xv.x, a.x, d0); d1 = fmaf(xv.x, b.x, d1);
            xs = fmaf(xv.y, xv.y, xs); d0 = fmaf(xv.y, a.y, d0); d1 = fmaf(xv.y, b.y, d1);
            xs = fmaf(xv.z, xv.z, xs); d0 = fmaf(xv.z, a.z, d0); d1 = fmaf(xv.z, b.z, d1);
            xs = fmaf(xv.w, xv.w, xs); d0 = fmaf(xv.w, a.w, d0); d1 = fmaf(xv.w, b.w, d1);
        }
        float s0 = fmaf(-2.f, d0, xs) + scs[2 * lane];
        float s1 = fmaf(-2.f, d1, xs) + scs[2 * lane + 1];
        float bv = s0;
        int bi = 2 * lane;
        if (s1 < bv) { bv = s1; bi = 2 * lane + 1; }
        #pragma unroll
        for (int msk = 1; msk < 64; msk <<= 1) {
            float ov = __shfl_xor(bv, msk, 64);
            int oi = __shfl_xor(bi, msk, 64);
            if (ov < bv || (ov == bv && oi < bi)) { bv = ov; bi = oi; }
        }
        if (lane == 0) sbest[t] = bi;
    }
    __syncthreads();

    // ---- epilogue: out[t][:] = pc[best[t]][:] * keep ----
    #pragma unroll
    for (int it = 0; it < 8; ++it) {
        int idx = it * 256 + tid;
        int t = idx >> 6;
        int f4 = idx & 63;
        int best = sbest[t];
        float mval = masks[t0 + t] ? 0.f : 1.f;
        float4 v = *(const float4*)(pc + (size_t)best * DOUT + f4 * 4);
        v.x *= mval; v.y *= mval; v.z *= mval; v.w *= mval;
        *(float4*)(out + (size_t)(t0 + t) * DOUT + f4 * 4) = v;
    }
}

extern "C" void kernel_launch(void* const* d_in, const int* in_sizes, int n_in,
                              void* d_out, int out_size, void* d_ws, size_t ws_size,
                              hipStream_t stream) {
    const float* x = (const float*)d_in[0];
    const float* centers = (const float*)d_in[1];
    const float* proj_w = (const float*)d_in[2];
    const float* proj_b = (const float*)d_in[3];
    const unsigned char* masks = (const unsigned char*)d_in[4];
    float* out = (float*)d_out;

    char* ws = (char*)d_ws;
    float* pc   = (float*)(ws);                         // 131072 B
    float* csq  = (float*)(ws + 131072);                // 512 B
    bf16_t* cbh = (bf16_t*)(ws + 131584);               // 65536 B
    bf16_t* cbm = (bf16_t*)(ws + 131584 + 65536);
    bf16_t* cbl = (bf16_t*)(ws + 131584 + 131072);

    precompute_kernel<<<NCLUST, 256, 0, stream>>>(centers, proj_w, proj_b,
                                                  pc, csq, cbh, cbm, cbl);
    cluster_mfma_kernel<<<N_TOKENS / BM, 256, 0, stream>>>(x, centers, cbh, cbm, cbl,
                                                           csq, pc, masks, out);
}

// Round 5
// 127.201 us; speedup vs baseline: 1.0167x; 1.0167x over previous
//
#include <hip/hip_runtime.h>
#include <cmath>

#define N_TOKENS 65536
#define DIM 256
#define NCLUST 128
#define DOUT 256

#define BM 64    // tokens per block (4 waves x 16 tokens)
#define EPS 2e-3f

typedef __bf16 bf16_t;
typedef bf16_t bf16x8 __attribute__((ext_vector_type(8)));
typedef float f32x4 __attribute__((ext_vector_type(4)));

__device__ inline void split3(float x, bf16_t& h, bf16_t& m, bf16_t& l) {
    h = (bf16_t)x;
    float r = x - (float)h;       // exact
    m = (bf16_t)r;
    float r2 = r - (float)m;      // exact
    l = (bf16_t)r2;
}

// ---------------- kernel 1: precompute -----------------------------
// csq[n] (round-1 float butterfly, bitwise-matching the passing recheck),
// pc[n][o] = centers@proj_w^T + b,
// cb[n][plane][k]: interleaved 3-way bf16 split planes (plane-major per row).
__global__ __launch_bounds__(256) void precompute_kernel(
    const float* __restrict__ centers,
    const float* __restrict__ proj_w,
    const float* __restrict__ proj_b,
    float* __restrict__ pc,
    float* __restrict__ csq,
    bf16_t* __restrict__ cb)
{
    __shared__ float cl[DIM];
    __shared__ float red[4];
    const int n = blockIdx.x;
    const int tid = threadIdx.x;

    float cv = centers[n * DIM + tid];
    cl[tid] = cv;

    bf16_t h, m, l;
    split3(cv, h, m, l);
    cb[(size_t)n * 768 + 0 * 256 + tid] = h;
    cb[(size_t)n * 768 + 1 * 256 + tid] = m;
    cb[(size_t)n * 768 + 2 * 256 + tid] = l;

    float s = cv * cv;
    #pragma unroll
    for (int off = 32; off >= 1; off >>= 1)
        s += __shfl_down(s, off, 64);
    if ((tid & 63) == 0) red[tid >> 6] = s;
    __syncthreads();
    if (tid == 0) csq[n] = (red[0] + red[1]) + (red[2] + red[3]);

    float acc = 0.f;
    const float* wrow = proj_w + (size_t)tid * DIM;
    #pragma unroll 4
    for (int d = 0; d < DIM; d += 4) {
        float4 w = *(const float4*)(wrow + d);
        acc = fmaf(w.x, cl[d + 0], acc);
        acc = fmaf(w.y, cl[d + 1], acc);
        acc = fmaf(w.z, cl[d + 2], acc);
        acc = fmaf(w.w, cl[d + 3], acc);
    }
    pc[(size_t)n * DOUT + tid] = acc + proj_b[tid];
}

// ---------------- kernel 2: barrier-free MFMA scores + argmin -----------
__global__ __launch_bounds__(256, 4) void cluster_mfma_kernel(
    const float* __restrict__ x,
    const float* __restrict__ centers,
    const bf16_t* __restrict__ cb,
    const float* __restrict__ csq,
    const float* __restrict__ pc,
    const unsigned char* __restrict__ masks,
    float* __restrict__ out)
{
    __shared__ int scnt[4][16];
    __shared__ int sbest[4][16];

    const int tid = threadIdx.x;
    const int lane = tid & 63;
    const int wid = tid >> 6;
    const int lr = lane & 15;
    const int lg = lane >> 4;
    const int t0 = blockIdx.x * BM;
    const int tw = t0 + wid * 16;      // this wave's 16 tokens

    // per-lane csq for its 8 cluster columns (c = nr*16 + lr)
    float myc[8];
    #pragma unroll
    for (int nr = 0; nr < 8; ++nr) myc[nr] = csq[nr * 16 + lr];

    f32x4 acc[8];
    #pragma unroll
    for (int nr = 0; nr < 8; ++nr) acc[nr] = (f32x4){0.f, 0.f, 0.f, 0.f};

    // A: row = lr (token tw+lr), k = lg*8 + j   (fp32 direct from global)
    const float* abase = x + (size_t)(tw + lr) * DIM + lg * 8;
    // B: col = lr (+nr*16), k = lg*8 + j, planes at +256/+512 elems
    const bf16_t* bbase = cb + (size_t)lr * 768 + lg * 8;

    #pragma unroll 2
    for (int ks = 0; ks < 8; ++ks) {
        float4 a0 = *(const float4*)(abase + ks * 32);
        float4 a1 = *(const float4*)(abase + ks * 32 + 4);
        float xv[8] = {a0.x, a0.y, a0.z, a0.w, a1.x, a1.y, a1.z, a1.w};
        bf16x8 ah, am, al;
        #pragma unroll
        for (int e = 0; e < 8; ++e) {
            bf16_t h, m, l;
            split3(xv[e], h, m, l);
            ah[e] = h; am[e] = m; al[e] = l;
        }
        #pragma unroll
        for (int nr = 0; nr < 8; ++nr) {
            const bf16_t* p = bbase + nr * (16 * 768) + ks * 32;
            bf16x8 bh = *(const bf16x8*)(p);
            bf16x8 bm = *(const bf16x8*)(p + 256);
            bf16x8 bl = *(const bf16x8*)(p + 512);
            f32x4 c4 = acc[nr];
            c4 = __builtin_amdgcn_mfma_f32_16x16x32_bf16(al, bh, c4, 0, 0, 0);
            c4 = __builtin_amdgcn_mfma_f32_16x16x32_bf16(ah, bl, c4, 0, 0, 0);
            c4 = __builtin_amdgcn_mfma_f32_16x16x32_bf16(am, bm, c4, 0, 0, 0);
            c4 = __builtin_amdgcn_mfma_f32_16x16x32_bf16(am, bh, c4, 0, 0, 0);
            c4 = __builtin_amdgcn_mfma_f32_16x16x32_bf16(ah, bm, c4, 0, 0, 0);
            c4 = __builtin_amdgcn_mfma_f32_16x16x32_bf16(ah, bh, c4, 0, 0, 0);
            acc[nr] = c4;
        }
    }

    // ---- per-wave argmin + EPS count ----
    // C layout: col(cluster) = lr (+nr*16), row(token) = lg*4 + reg
    #pragma unroll
    for (int reg = 0; reg < 4; ++reg) {
        float bv = INFINITY;
        int bi = 0;
        #pragma unroll
        for (int nr = 0; nr < 8; ++nr) {
            float v = fmaf(-2.f, acc[nr][reg], myc[nr]);
            int c = nr * 16 + lr;
            if (v < bv) { bv = v; bi = c; }
        }
        #pragma unroll
        for (int msk = 1; msk < 16; msk <<= 1) {
            float ov = __shfl_xor(bv, msk, 64);
            int oi = __shfl_xor(bi, msk, 64);
            if (ov < bv || (ov == bv && oi < bi)) { bv = ov; bi = oi; }
        }
        float thr = bv + EPS;
        int cnt = 0;
        #pragma unroll
        for (int nr = 0; nr < 8; ++nr) {
            float v = fmaf(-2.f, acc[nr][reg], myc[nr]);
            cnt += (v <= thr) ? 1 : 0;
        }
        #pragma unroll
        for (int msk = 1; msk < 16; msk <<= 1)
            cnt += __shfl_xor(cnt, msk, 64);
        if (lr == 0) {
            sbest[wid][lg * 4 + reg] = bi;
            scnt[wid][lg * 4 + reg] = cnt;
        }
    }
    __syncthreads();

    // ---- exact fp32 recheck for near-tie tokens (rare) ----
    // Bitwise round-1 arithmetic: sequential-k fmaf dot & xsq,
    // d2 = fmaf(-2,dot,xsq) + csq, lexicographic (value,idx) min.
    for (int tt = 0; tt < 16; ++tt) {
        if (scnt[wid][tt] < 2) continue;   // wave-uniform
        const float4* xr = (const float4*)(x + (size_t)(tw + tt) * DIM);
        const float4* c0 = (const float4*)(centers + (size_t)(2 * lane) * DIM);
        const float4* c1 = (const float4*)(centers + (size_t)(2 * lane + 1) * DIM);
        float xs = 0.f, d0 = 0.f, d1 = 0.f;
        #pragma unroll 4
        for (int k4 = 0; k4 < 64; ++k4) {
            float4 xv = xr[k4];
            float4 a = c0[k4];
            float4 b = c1[k4];
            xs = fmaf(xv.x, xv.x, xs); d0 = fmaf(xv.x, a.x, d0); d1 = fmaf(xv.x, b.x, d1);
            xs = fmaf(xv.y, xv.y, xs); d0 = fmaf(xv.y, a.y, d0); d1 = fmaf(xv.y, b.y, d1);
            xs = fmaf(xv.z, xv.z, xs); d0 = fmaf(xv.z, a.z, d0); d1 = fmaf(xv.z, b.z, d1);
            xs = fmaf(xv.w, xv.w, xs); d0 = fmaf(xv.w, a.w, d0); d1 = fmaf(xv.w, b.w, d1);
        }
        float s0 = fmaf(-2.f, d0, xs) + csq[2 * lane];
        float s1 = fmaf(-2.f, d1, xs) + csq[2 * lane + 1];
        float bv = s0;
        int bi = 2 * lane;
        if (s1 < bv) { bv = s1; bi = 2 * lane + 1; }
        #pragma unroll
        for (int msk = 1; msk < 64; msk <<= 1) {
            float ov = __shfl_xor(bv, msk, 64);
            int oi = __shfl_xor(bi, msk, 64);
            if (ov < bv || (ov == bv && oi < bi)) { bv = ov; bi = oi; }
        }
        if (lane == 0) sbest[wid][tt] = bi;
    }
    __syncthreads();

    // ---- epilogue: out[t][:] = pc[best[t]][:] * keep ----
    #pragma unroll
    for (int it = 0; it < 16; ++it) {
        int idx = it * 256 + tid;
        int t = idx >> 6;
        int f4 = idx & 63;
        int best = sbest[t >> 4][t & 15];
        float mval = masks[t0 + t] ? 0.f : 1.f;
        float4 v = *(const float4*)(pc + (size_t)best * DOUT + f4 * 4);
        v.x *= mval; v.y *= mval; v.z *= mval; v.w *= mval;
        *(float4*)(out + (size_t)(t0 + t) * DOUT + f4 * 4) = v;
    }
}

extern "C" void kernel_launch(void* const* d_in, const int* in_sizes, int n_in,
                              void* d_out, int out_size, void* d_ws, size_t ws_size,
                              hipStream_t stream) {
    const float* x = (const float*)d_in[0];
    const float* centers = (const float*)d_in[1];
    const float* proj_w = (const float*)d_in[2];
    const float* proj_b = (const float*)d_in[3];
    const unsigned char* masks = (const unsigned char*)d_in[4];
    float* out = (float*)d_out;

    char* ws = (char*)d_ws;
    float* pc   = (float*)(ws);                 // 131072 B
    float* csq  = (float*)(ws + 131072);        // 512 B
    bf16_t* cb  = (bf16_t*)(ws + 131584);       // 128*768*2 = 196608 B

    precompute_kernel<<<NCLUST, 256, 0, stream>>>(centers, proj_w, proj_b,
                                                  pc, csq, cb);
    cluster_mfma_kernel<<<N_TOKENS / BM, 256, 0, stream>>>(x, centers, cb,
                                                           csq, pc, masks, out);
}

// Round 6
// 90.648 us; speedup vs baseline: 1.4267x; 1.4032x over previous
//
#include <hip/hip_runtime.h>
#include <cmath>

#define N_TOKENS 65536
#define DIM 256
#define NCLUST 128
#define DOUT 256

#define BM 64    // tokens per block: 2 waveM x 32 tokens
#define EPS 2e-3f

typedef __bf16 bf16_t;
typedef bf16_t bf16x8 __attribute__((ext_vector_type(8)));
typedef float f32x4 __attribute__((ext_vector_type(4)));

__device__ inline void split3(float x, bf16_t& h, bf16_t& m, bf16_t& l) {
    h = (bf16_t)x;
    float r = x - (float)h;       // exact
    m = (bf16_t)r;
    float r2 = r - (float)m;      // exact
    l = (bf16_t)r2;
}

// ---------------- kernel 1: precompute (unchanged) ----------------------
// csq[n] (round-1 float butterfly, bitwise-matching the passing recheck),
// pc[n][o] = centers@proj_w^T + b,
// cb[n][plane][k]: interleaved 3-way bf16 split planes (plane-major per row).
__global__ __launch_bounds__(256) void precompute_kernel(
    const float* __restrict__ centers,
    const float* __restrict__ proj_w,
    const float* __restrict__ proj_b,
    float* __restrict__ pc,
    float* __restrict__ csq,
    bf16_t* __restrict__ cb)
{
    __shared__ float cl[DIM];
    __shared__ float red[4];
    const int n = blockIdx.x;
    const int tid = threadIdx.x;

    float cv = centers[n * DIM + tid];
    cl[tid] = cv;

    bf16_t h, m, l;
    split3(cv, h, m, l);
    cb[(size_t)n * 768 + 0 * 256 + tid] = h;
    cb[(size_t)n * 768 + 1 * 256 + tid] = m;
    cb[(size_t)n * 768 + 2 * 256 + tid] = l;

    float s = cv * cv;
    #pragma unroll
    for (int off = 32; off >= 1; off >>= 1)
        s += __shfl_down(s, off, 64);
    if ((tid & 63) == 0) red[tid >> 6] = s;
    __syncthreads();
    if (tid == 0) csq[n] = (red[0] + red[1]) + (red[2] + red[3]);

    float acc = 0.f;
    const float* wrow = proj_w + (size_t)tid * DIM;
    #pragma unroll 4
    for (int d = 0; d < DIM; d += 4) {
        float4 w = *(const float4*)(wrow + d);
        acc = fmaf(w.x, cl[d + 0], acc);
        acc = fmaf(w.y, cl[d + 1], acc);
        acc = fmaf(w.z, cl[d + 2], acc);
        acc = fmaf(w.w, cl[d + 3], acc);
    }
    pc[(size_t)n * DOUT + tid] = acc + proj_b[tid];
}

// ---------------- kernel 2: pipelined MFMA scores + argmin --------------
__global__ __launch_bounds__(256, 3) void cluster_mfma_kernel(
    const float* __restrict__ x,
    const float* __restrict__ centers,
    const bf16_t* __restrict__ cb,
    const float* __restrict__ csq,
    const float* __restrict__ pc,
    const unsigned char* __restrict__ masks,
    float* __restrict__ out)
{
    __shared__ float sminv[2][BM];
    __shared__ int   smini[2][BM];
    __shared__ float sminT[BM];
    __shared__ int   scnt[BM];
    __shared__ int   sbest[BM];

    const int tid = threadIdx.x;
    const int lane = tid & 63;
    const int wid = tid >> 6;
    const int waveM = wid >> 1;   // token half: waveM*32
    const int waveN = wid & 1;    // cluster half: waveN*64
    const int lr = lane & 15;
    const int lg = lane >> 4;
    const int t0 = blockIdx.x * BM;

    // per-lane csq for this wave's 4 cluster columns
    float myc[4];
    #pragma unroll
    for (int nr = 0; nr < 4; ++nr) myc[nr] = csq[waveN * 64 + nr * 16 + lr];

    f32x4 acc[2][4];
    #pragma unroll
    for (int mr = 0; mr < 2; ++mr)
        #pragma unroll
        for (int nr = 0; nr < 4; ++nr)
            acc[mr][nr] = (f32x4){0.f, 0.f, 0.f, 0.f};

    // A: token = t0 + waveM*32 + mr*16 + lr, k = lg*8 + j (fp32 from global)
    const float* abase = x + (size_t)(t0 + waveM * 32 + lr) * DIM + lg * 8;
    // B: cluster = waveN*64 + nr*16 + lr, k = lg*8 + j, planes +256/+512
    const bf16_t* bbase = cb + (size_t)(waveN * 64 + lr) * 768 + lg * 8;

    // parity-double-buffered register pipeline (all indices fold after unroll)
    bf16x8 fh[2][4], fm[2][4], fl[2][4];
    float4 ax[2][2][2];

    #define LOADB(par, ksv)                                            \
        _Pragma("unroll")                                              \
        for (int nr = 0; nr < 4; ++nr) {                               \
            const bf16_t* p = bbase + nr * (16 * 768) + (ksv) * 32;    \
            fh[par][nr] = *(const bf16x8*)(p);                         \
            fm[par][nr] = *(const bf16x8*)(p + 256);                   \
            fl[par][nr] = *(const bf16x8*)(p + 512);                   \
        }
    #define LOADA(par, ksv)                                            \
        _Pragma("unroll")                                              \
        for (int mr = 0; mr < 2; ++mr) {                               \
            const float* ap = abase + mr * (16 * DIM) + (ksv) * 32;    \
            ax[par][mr][0] = *(const float4*)(ap);                     \
            ax[par][mr][1] = *(const float4*)(ap + 4);                 \
        }

    LOADA(0, 0);
    LOADB(0, 0);

    #pragma unroll
    for (int ks = 0; ks < 8; ++ks) {
        const int cur = ks & 1;
        const int nxt = cur ^ 1;
        if (ks < 7) {
            LOADA(nxt, ks + 1);
            LOADB(nxt, ks + 1);
        }
        bf16x8 ah[2], am[2], al[2];
        #pragma unroll
        for (int mr = 0; mr < 2; ++mr) {
            float xv[8] = {ax[cur][mr][0].x, ax[cur][mr][0].y,
                           ax[cur][mr][0].z, ax[cur][mr][0].w,
                           ax[cur][mr][1].x, ax[cur][mr][1].y,
                           ax[cur][mr][1].z, ax[cur][mr][1].w};
            #pragma unroll
            for (int e = 0; e < 8; ++e) {
                bf16_t h, m, l;
                split3(xv[e], h, m, l);
                ah[mr][e] = h; am[mr][e] = m; al[mr][e] = l;
            }
        }
        #pragma unroll
        for (int mr = 0; mr < 2; ++mr) {
            #pragma unroll
            for (int nr = 0; nr < 4; ++nr) {
                f32x4 c4 = acc[mr][nr];
                c4 = __builtin_amdgcn_mfma_f32_16x16x32_bf16(al[mr], fh[cur][nr], c4, 0, 0, 0);
                c4 = __builtin_amdgcn_mfma_f32_16x16x32_bf16(ah[mr], fl[cur][nr], c4, 0, 0, 0);
                c4 = __builtin_amdgcn_mfma_f32_16x16x32_bf16(am[mr], fm[cur][nr], c4, 0, 0, 0);
                c4 = __builtin_amdgcn_mfma_f32_16x16x32_bf16(am[mr], fh[cur][nr], c4, 0, 0, 0);
                c4 = __builtin_amdgcn_mfma_f32_16x16x32_bf16(ah[mr], fm[cur][nr], c4, 0, 0, 0);
                c4 = __builtin_amdgcn_mfma_f32_16x16x32_bf16(ah[mr], fh[cur][nr], c4, 0, 0, 0);
                acc[mr][nr] = c4;
            }
        }
    }
    #undef LOADA
    #undef LOADB

    // ---- pass 1: approx argmin (score = csq - 2*dot), per half ----
    // C layout: col(cluster) = lr (+nr*16), row(token) = lg*4 + reg
    #pragma unroll
    for (int mr = 0; mr < 2; ++mr) {
        #pragma unroll
        for (int reg = 0; reg < 4; ++reg) {
            float bv = INFINITY;
            int bi = 0;
            #pragma unroll
            for (int nr = 0; nr < 4; ++nr) {
                float v = fmaf(-2.f, acc[mr][nr][reg], myc[nr]);
                int c = waveN * 64 + nr * 16 + lr;
                if (v < bv) { bv = v; bi = c; }
            }
            #pragma unroll
            for (int msk = 1; msk < 16; msk <<= 1) {
                float ov = __shfl_xor(bv, msk, 64);
                int oi = __shfl_xor(bi, msk, 64);
                if (ov < bv || (ov == bv && oi < bi)) { bv = ov; bi = oi; }
            }
            if (lr == 0) {
                int t = waveM * 32 + mr * 16 + lg * 4 + reg;
                sminv[waveN][t] = bv;
                smini[waveN][t] = bi;
            }
        }
    }
    __syncthreads();
    if (tid < BM) {
        float v0 = sminv[0][tid], v1 = sminv[1][tid];
        sminT[tid] = fminf(v0, v1);
        sbest[tid] = (v1 < v0) ? smini[1][tid] : smini[0][tid];
        scnt[tid] = 0;
    }
    __syncthreads();

    // ---- pass 2: count candidates within EPS of the min ----
    #pragma unroll
    for (int mr = 0; mr < 2; ++mr) {
        #pragma unroll
        for (int reg = 0; reg < 4; ++reg) {
            int t = waveM * 32 + mr * 16 + lg * 4 + reg;
            float thr = sminT[t] + EPS;
            int cnt = 0;
            #pragma unroll
            for (int nr = 0; nr < 4; ++nr) {
                float v = fmaf(-2.f, acc[mr][nr][reg], myc[nr]);
                cnt += (v <= thr) ? 1 : 0;
            }
            if (cnt > 0) atomicAdd(&scnt[t], cnt);
        }
    }
    __syncthreads();

    // ---- pass 3: exact fp32 recheck for near-tie tokens (rare) ----
    // Bitwise round-1 arithmetic: sequential-k fmaf dot & xsq,
    // d2 = fmaf(-2,dot,xsq) + csq, lexicographic (value,idx) min.
    for (int tt = 0; tt < 16; ++tt) {
        int t = wid * 16 + tt;
        if (scnt[t] < 2) continue;   // wave-uniform
        const float4* xr = (const float4*)(x + (size_t)(t0 + t) * DIM);
        const float4* c0 = (const float4*)(centers + (size_t)(2 * lane) * DIM);
        const float4* c1 = (const float4*)(centers + (size_t)(2 * lane + 1) * DIM);
        float xs = 0.f, d0 = 0.f, d1 = 0.f;
        #pragma unroll 4
        for (int k4 = 0; k4 < 64; ++k4) {
            float4 xv = xr[k4];
            float4 a = c0[k4];
            float4 b = c1[k4];
            xs = fmaf(xv.x, xv.x, xs); d0 = fmaf(xv.x, a.x, d0); d1 = fmaf(xv.x, b.x, d1);
            xs = fmaf(xv.y, xv.y, xs); d0 = fmaf(xv.y, a.y, d0); d1 = fmaf(xv.y, b.y, d1);
            xs = fmaf(xv.z, xv.z, xs); d0 = fmaf(xv.z, a.z, d0); d1 = fmaf(xv.z, b.z, d1);
            xs = fmaf(xv.w, xv.w, xs); d0 = fmaf(xv.w, a.w, d0); d1 = fmaf(xv.w, b.w, d1);
        }
        float s0 = fmaf(-2.f, d0, xs) + csq[2 * lane];
        float s1 = fmaf(-2.f, d1, xs) + csq[2 * lane + 1];
        float bv = s0;
        int bi = 2 * lane;
        if (s1 < bv) { bv = s1; bi = 2 * lane + 1; }
        #pragma unroll
        for (int msk = 1; msk < 64; msk <<= 1) {
            float ov = __shfl_xor(bv, msk, 64);
            int oi = __shfl_xor(bi, msk, 64);
            if (ov < bv || (ov == bv && oi < bi)) { bv = ov; bi = oi; }
        }
        if (lane == 0) sbest[t] = bi;
    }
    __syncthreads();

    // ---- epilogue: out[t][:] = pc[best[t]][:] * keep ----
    #pragma unroll
    for (int it = 0; it < 16; ++it) {
        int idx = it * 256 + tid;
        int t = idx >> 6;
        int f4 = idx & 63;
        int best = sbest[t];
        float mval = masks[t0 + t] ? 0.f : 1.f;
        float4 v = *(const float4*)(pc + (size_t)best * DOUT + f4 * 4);
        v.x *= mval; v.y *= mval; v.z *= mval; v.w *= mval;
        *(float4*)(out + (size_t)(t0 + t) * DOUT + f4 * 4) = v;
    }
}

extern "C" void kernel_launch(void* const* d_in, const int* in_sizes, int n_in,
                              void* d_out, int out_size, void* d_ws, size_t ws_size,
                              hipStream_t stream) {
    const float* x = (const float*)d_in[0];
    const float* centers = (const float*)d_in[1];
    const float* proj_w = (const float*)d_in[2];
    const float* proj_b = (const float*)d_in[3];
    const unsigned char* masks = (const unsigned char*)d_in[4];
    float* out = (float*)d_out;

    char* ws = (char*)d_ws;
    float* pc   = (float*)(ws);                 // 131072 B
    float* csq  = (float*)(ws + 131072);        // 512 B
    bf16_t* cb  = (bf16_t*)(ws + 131584);       // 128*768*2 = 196608 B

    precompute_kernel<<<NCLUST, 256, 0, stream>>>(centers, proj_w, proj_b,
                                                  pc, csq, cb);
    cluster_mfma_kernel<<<N_TOKENS / BM, 256, 0, stream>>>(x, centers, cb,
                                                           csq, pc, masks, out);
}

// Round 7
// 60.042 us; speedup vs baseline: 2.1540x; 1.5098x over previous
//
#include <hip/hip_runtime.h>
#include <cmath>

#define N_TOKENS 65536
#define DIM 256
#define NCLUST 128
#define DOUT 256

#define BM 64    // tokens per block: 2 waveM x 32 tokens, 2 waveN x 64 clusters
#define EPS 2e-3f

typedef _Float16 f16_t;
typedef f16_t f16x8 __attribute__((ext_vector_type(8)));
typedef float f32x4 __attribute__((ext_vector_type(4)));

__device__ inline void split2(float x, f16_t& h, f16_t& m) {
    h = (f16_t)x;
    float r = x - (float)h;   // exact (Sterbenz)
    m = (f16_t)r;             // dropped residual ~2^-22 relative
}

__device__ inline void lds_load16(void* lds, const void* g) {
    __builtin_amdgcn_global_load_lds(
        (const __attribute__((address_space(1))) unsigned int*)g,
        (__attribute__((address_space(3))) unsigned int*)lds, 16, 0, 0);
}

// ---------------- kernel 1: precompute ----------------------------------
// csq[n] (round-1 float butterfly, bitwise-matching the passing recheck),
// pc[n][o] = centers@proj_w^T + b,
// cbs: fp16 2-plane split of centers, PRE-SWIZZLED in the exact LDS image:
//   k-step s (32 k), cluster n, chunk pc = (plane*4 + k8) ^ (n&7), 8 halves.
__global__ __launch_bounds__(256) void precompute_kernel(
    const float* __restrict__ centers,
    const float* __restrict__ proj_w,
    const float* __restrict__ proj_b,
    float* __restrict__ pc,
    float* __restrict__ csq,
    f16_t* __restrict__ cbs)
{
    __shared__ float cl[DIM];
    __shared__ float red[4];
    const int n = blockIdx.x;
    const int tid = threadIdx.x;

    float cv = centers[n * DIM + tid];
    cl[tid] = cv;

    f16_t h, m;
    split2(cv, h, m);
    {
        int s  = tid >> 5;
        int k8 = (tid >> 3) & 3;
        int j  = tid & 7;
        size_t base = (size_t)(s * 128 + n) * 8;
        cbs[(base + ((k8    ) ^ (n & 7))) * 8 + j] = h;   // plane 0 (high)
        cbs[(base + ((4 + k8) ^ (n & 7))) * 8 + j] = m;   // plane 1 (mid)
    }

    float s = cv * cv;
    #pragma unroll
    for (int off = 32; off >= 1; off >>= 1)
        s += __shfl_down(s, off, 64);
    if ((tid & 63) == 0) red[tid >> 6] = s;
    __syncthreads();
    if (tid == 0) csq[n] = (red[0] + red[1]) + (red[2] + red[3]);

    float acc = 0.f;
    const float* wrow = proj_w + (size_t)tid * DIM;
    #pragma unroll 4
    for (int d = 0; d < DIM; d += 4) {
        float4 w = *(const float4*)(wrow + d);
        acc = fmaf(w.x, cl[d + 0], acc);
        acc = fmaf(w.y, cl[d + 1], acc);
        acc = fmaf(w.z, cl[d + 2], acc);
        acc = fmaf(w.w, cl[d + 3], acc);
    }
    pc[(size_t)tid + (size_t)n * DOUT] = acc + proj_b[tid];
}

// ---------------- kernel 2: 2-phase gll-pipelined MFMA + argmin ---------
__global__ __launch_bounds__(256) void cluster_mfma_kernel(
    const float* __restrict__ x,
    const float* __restrict__ centers,
    const f16_t* __restrict__ cbs,
    const float* __restrict__ csq,
    const float* __restrict__ pc,
    const unsigned char* __restrict__ masks,
    float* __restrict__ out)
{
    __shared__ float As[2][BM * 32];        // fp32 x-slice, swizzled chunks
    __shared__ f16_t Bs[2][NCLUST * 64];    // fp16 2-plane B-slice (LDS image)
    __shared__ float sminv[2][BM];
    __shared__ int   smini[2][BM];
    __shared__ float sminT[BM];
    __shared__ int   scnt[BM];
    __shared__ int   sbest[BM];

    const int tid = threadIdx.x;
    const int lane = tid & 63;
    const int wid = tid >> 6;
    const int waveM = wid >> 1;   // token half: waveM*32
    const int waveN = wid & 1;    // cluster half: waveN*64
    const int lr = lane & 15;
    const int lg = lane >> 4;
    const int t0 = blockIdx.x * BM;

    float myc[4];
    #pragma unroll
    for (int nr = 0; nr < 4; ++nr) myc[nr] = csq[waveN * 64 + nr * 16 + lr];

    f32x4 acc[2][4];
    #pragma unroll
    for (int mr = 0; mr < 2; ++mr)
        #pragma unroll
        for (int nr = 0; nr < 4; ++nr)
            acc[mr][nr] = (f32x4){0.f, 0.f, 0.f, 0.f};

    const char* cbsb = (const char*)cbs;

    // A stage: 512 chunks of 16B; LDS linear, global chunk pre-swizzled.
    // B stage: 1024 chunks of 16B; straight linear copy (swizzle baked in).
    #define STAGE(buf, s) do {                                               \
        _Pragma("unroll")                                                    \
        for (int it = 0; it < 2; ++it) {                                     \
            int o = it * 256 + tid;                                          \
            int t = o >> 3;                                                  \
            int c = o & 7;                                                   \
            lds_load16((char*)As[buf] + o * 16,                              \
                (const char*)(x + (size_t)(t0 + t) * DIM + (s) * 32          \
                              + ((c ^ (t & 7)) << 2)));                      \
        }                                                                    \
        _Pragma("unroll")                                                    \
        for (int it = 0; it < 4; ++it) {                                     \
            int o = it * 256 + tid;                                          \
            lds_load16((char*)Bs[buf] + o * 16,                              \
                       cbsb + (size_t)(s) * 16384 + o * 16);                 \
        }                                                                    \
    } while (0)

    STAGE(0, 0);
    __syncthreads();

    #pragma unroll
    for (int s = 0; s < 8; ++s) {
        const int cur = s & 1;
        if (s < 7) STAGE(cur ^ 1, s + 1);

        // A fragments from LDS + split2 (row = lr, k = lg*8 + j)
        f16x8 ah[2], am[2];
        #pragma unroll
        for (int mr = 0; mr < 2; ++mr) {
            int t = waveM * 32 + mr * 16 + lr;
            const char* ab = (const char*)As[cur] + t * 128;
            float4 v0 = *(const float4*)(ab + ((((lg * 2)    ) ^ (t & 7)) << 4));
            float4 v1 = *(const float4*)(ab + ((((lg * 2) + 1) ^ (t & 7)) << 4));
            float xv[8] = {v0.x, v0.y, v0.z, v0.w, v1.x, v1.y, v1.z, v1.w};
            #pragma unroll
            for (int e = 0; e < 8; ++e) {
                f16_t h, m;
                split2(xv[e], h, m);
                ah[mr][e] = h; am[mr][e] = m;
            }
        }
        // B fragments + MFMA (3 terms: am*bh, ah*bm, ah*bh)
        #pragma unroll
        for (int nr = 0; nr < 4; ++nr) {
            int n = waveN * 64 + nr * 16 + lr;
            const char* bb = (const char*)Bs[cur] + n * 128;
            f16x8 bh = *(const f16x8*)(bb + (((lg    ) ^ (n & 7)) << 4));
            f16x8 bm = *(const f16x8*)(bb + (((4 + lg) ^ (n & 7)) << 4));
            #pragma unroll
            for (int mr = 0; mr < 2; ++mr) {
                f32x4 c4 = acc[mr][nr];
                c4 = __builtin_amdgcn_mfma_f32_16x16x32_f16(am[mr], bh, c4, 0, 0, 0);
                c4 = __builtin_amdgcn_mfma_f32_16x16x32_f16(ah[mr], bm, c4, 0, 0, 0);
                c4 = __builtin_amdgcn_mfma_f32_16x16x32_f16(ah[mr], bh, c4, 0, 0, 0);
                acc[mr][nr] = c4;
            }
        }
        __syncthreads();
    }
    #undef STAGE

    // ---- pass 1: approx argmin (score = csq - 2*dot), per half ----
    // C layout: col(cluster) = lr (+nr*16), row(token) = lg*4 + reg
    #pragma unroll
    for (int mr = 0; mr < 2; ++mr) {
        #pragma unroll
        for (int reg = 0; reg < 4; ++reg) {
            float bv = INFINITY;
            int bi = 0;
            #pragma unroll
            for (int nr = 0; nr < 4; ++nr) {
                float v = fmaf(-2.f, acc[mr][nr][reg], myc[nr]);
                int c = waveN * 64 + nr * 16 + lr;
                if (v < bv) { bv = v; bi = c; }
            }
            #pragma unroll
            for (int msk = 1; msk < 16; msk <<= 1) {
                float ov = __shfl_xor(bv, msk, 64);
                int oi = __shfl_xor(bi, msk, 64);
                if (ov < bv || (ov == bv && oi < bi)) { bv = ov; bi = oi; }
            }
            if (lr == 0) {
                int t = waveM * 32 + mr * 16 + lg * 4 + reg;
                sminv[waveN][t] = bv;
                smini[waveN][t] = bi;
            }
        }
    }
    __syncthreads();
    if (tid < BM) {
        float v0 = sminv[0][tid], v1 = sminv[1][tid];
        sminT[tid] = fminf(v0, v1);
        sbest[tid] = (v1 < v0) ? smini[1][tid] : smini[0][tid];
        scnt[tid] = 0;
    }
    __syncthreads();

    // ---- pass 2: count candidates within EPS of the min ----
    #pragma unroll
    for (int mr = 0; mr < 2; ++mr) {
        #pragma unroll
        for (int reg = 0; reg < 4; ++reg) {
            int t = waveM * 32 + mr * 16 + lg * 4 + reg;
            float thr = sminT[t] + EPS;
            int cnt = 0;
            #pragma unroll
            for (int nr = 0; nr < 4; ++nr) {
                float v = fmaf(-2.f, acc[mr][nr][reg], myc[nr]);
                cnt += (v <= thr) ? 1 : 0;
            }
            if (cnt > 0) atomicAdd(&scnt[t], cnt);
        }
    }
    __syncthreads();

    // ---- pass 3: exact fp32 recheck for near-tie tokens (rare) ----
    // Bitwise round-1 arithmetic: sequential-k fmaf dot & xsq,
    // d2 = fmaf(-2,dot,xsq) + csq, lexicographic (value,idx) min.
    for (int tt = 0; tt < 16; ++tt) {
        int t = wid * 16 + tt;
        if (scnt[t] < 2) continue;   // wave-uniform
        const float4* xr = (const float4*)(x + (size_t)(t0 + t) * DIM);
        const float4* c0 = (const float4*)(centers + (size_t)(2 * lane) * DIM);
        const float4* c1 = (const float4*)(centers + (size_t)(2 * lane + 1) * DIM);
        float xs = 0.f, d0 = 0.f, d1 = 0.f;
        #pragma unroll 4
        for (int k4 = 0; k4 < 64; ++k4) {
            float4 xv = xr[k4];
            float4 a = c0[k4];
            float4 b = c1[k4];
            xs = fmaf(xv.x, xv.x, xs); d0 = fmaf(xv.x, a.x, d0); d1 = fmaf(xv.x, b.x, d1);
            xs = fmaf(xv.y, xv.y, xs); d0 = fmaf(xv.y, a.y, d0); d1 = fmaf(xv.y, b.y, d1);
            xs = fmaf(xv.z, xv.z, xs); d0 = fmaf(xv.z, a.z, d0); d1 = fmaf(xv.z, b.z, d1);
            xs = fmaf(xv.w, xv.w, xs); d0 = fmaf(xv.w, a.w, d0); d1 = fmaf(xv.w, b.w, d1);
        }
        float s0 = fmaf(-2.f, d0, xs) + csq[2 * lane];
        float s1 = fmaf(-2.f, d1, xs) + csq[2 * lane + 1];
        float bv = s0;
        int bi = 2 * lane;
        if (s1 < bv) { bv = s1; bi = 2 * lane + 1; }
        #pragma unroll
        for (int msk = 1; msk < 64; msk <<= 1) {
            float ov = __shfl_xor(bv, msk, 64);
            int oi = __shfl_xor(bi, msk, 64);
            if (ov < bv || (ov == bv && oi < bi)) { bv = ov; bi = oi; }
        }
        if (lane == 0) sbest[t] = bi;
    }
    __syncthreads();

    // ---- epilogue: out[t][:] = pc[best[t]][:] * keep ----
    #pragma unroll
    for (int it = 0; it < 16; ++it) {
        int idx = it * 256 + tid;
        int t = idx >> 6;
        int f4 = idx & 63;
        int best = sbest[t];
        float mval = masks[t0 + t] ? 0.f : 1.f;
        float4 v = *(const float4*)(pc + (size_t)best * DOUT + f4 * 4);
        v.x *= mval; v.y *= mval; v.z *= mval; v.w *= mval;
        *(float4*)(out + (size_t)(t0 + t) * DOUT + f4 * 4) = v;
    }
}

extern "C" void kernel_launch(void* const* d_in, const int* in_sizes, int n_in,
                              void* d_out, int out_size, void* d_ws, size_t ws_size,
                              hipStream_t stream) {
    const float* x = (const float*)d_in[0];
    const float* centers = (const float*)d_in[1];
    const float* proj_w = (const float*)d_in[2];
    const float* proj_b = (const float*)d_in[3];
    const unsigned char* masks = (const unsigned char*)d_in[4];
    float* out = (float*)d_out;

    char* ws = (char*)d_ws;
    float* pc   = (float*)(ws);                 // 131072 B
    float* csq  = (float*)(ws + 131072);        // 512 B
    f16_t* cbs  = (f16_t*)(ws + 131584);        // 128*512*2 = 131072 B

    precompute_kernel<<<NCLUST, 256, 0, stream>>>(centers, proj_w, proj_b,
                                                  pc, csq, cbs);
    cluster_mfma_kernel<<<N_TOKENS / BM, 256, 0, stream>>>(x, centers, cbs,
                                                           csq, pc, masks, out);
}

// Round 8
// 57.248 us; speedup vs baseline: 2.2591x; 1.0488x over previous
//
#include <hip/hip_runtime.h>
#include <cmath>

#define N_TOKENS 65536
#define DIM 256
#define NCLUST 128
#define DOUT 256

#define BM 64    // tokens per block: 2 waveM x 32 tokens, 2 waveN x 64 clusters
#define EPS 2e-3f

typedef _Float16 f16_t;
typedef f16_t f16x8 __attribute__((ext_vector_type(8)));
typedef float f32x4 __attribute__((ext_vector_type(4)));

__device__ inline void split2(float x, f16_t& h, f16_t& m) {
    h = (f16_t)x;
    float r = x - (float)h;   // exact (Sterbenz)
    m = (f16_t)r;             // dropped residual ~2^-22 relative
}

__device__ inline void lds_load16(void* lds, const void* g) {
    __builtin_amdgcn_global_load_lds(
        (const __attribute__((address_space(1))) unsigned int*)g,
        (__attribute__((address_space(3))) unsigned int*)lds, 16, 0, 0);
}

// ---------------- kernel 1: precompute (unchanged from round 7) ---------
// csq[n] (round-1 float butterfly, bitwise-matching the passing recheck),
// pc[n][o] = centers@proj_w^T + b,
// cbs: fp16 2-plane split of centers, PRE-SWIZZLED in the exact LDS image:
//   k-step s (32 k), cluster n, chunk pc = (plane*4 + k8) ^ (n&7), 8 halves.
__global__ __launch_bounds__(256) void precompute_kernel(
    const float* __restrict__ centers,
    const float* __restrict__ proj_w,
    const float* __restrict__ proj_b,
    float* __restrict__ pc,
    float* __restrict__ csq,
    f16_t* __restrict__ cbs)
{
    __shared__ float cl[DIM];
    __shared__ float red[4];
    const int n = blockIdx.x;
    const int tid = threadIdx.x;

    float cv = centers[n * DIM + tid];
    cl[tid] = cv;

    f16_t h, m;
    split2(cv, h, m);
    {
        int s  = tid >> 5;
        int k8 = (tid >> 3) & 3;
        int j  = tid & 7;
        size_t base = (size_t)(s * 128 + n) * 8;
        cbs[(base + ((k8    ) ^ (n & 7))) * 8 + j] = h;   // plane 0 (high)
        cbs[(base + ((4 + k8) ^ (n & 7))) * 8 + j] = m;   // plane 1 (mid)
    }

    float s = cv * cv;
    #pragma unroll
    for (int off = 32; off >= 1; off >>= 1)
        s += __shfl_down(s, off, 64);
    if ((tid & 63) == 0) red[tid >> 6] = s;
    __syncthreads();
    if (tid == 0) csq[n] = (red[0] + red[1]) + (red[2] + red[3]);

    float acc = 0.f;
    const float* wrow = proj_w + (size_t)tid * DIM;
    #pragma unroll 4
    for (int d = 0; d < DIM; d += 4) {
        float4 w = *(const float4*)(wrow + d);
        acc = fmaf(w.x, cl[d + 0], acc);
        acc = fmaf(w.y, cl[d + 1], acc);
        acc = fmaf(w.z, cl[d + 2], acc);
        acc = fmaf(w.w, cl[d + 3], acc);
    }
    pc[(size_t)tid + (size_t)n * DOUT] = acc + proj_b[tid];
}

// ---------------- kernel 2: counted-vmcnt pipelined MFMA + argmin -------
__global__ __launch_bounds__(256) void cluster_mfma_kernel(
    const float* __restrict__ x,
    const float* __restrict__ centers,
    const f16_t* __restrict__ cbs,
    const float* __restrict__ csq,
    const float* __restrict__ pc,
    const unsigned char* __restrict__ masks,
    float* __restrict__ out)
{
    __shared__ float As[2][BM * 32];        // fp32 x-slice, swizzled chunks
    __shared__ f16_t Bs[2][NCLUST * 64];    // fp16 2-plane B-slice (LDS image)
    __shared__ float sminv[2][BM];
    __shared__ int   smini[2][BM];
    __shared__ float sminT[BM];
    __shared__ int   scnt[BM];
    __shared__ int   sbest[BM];

    const int tid = threadIdx.x;
    const int lane = tid & 63;
    const int wid = tid >> 6;
    const int waveM = wid >> 1;   // token half: waveM*32
    const int waveN = wid & 1;    // cluster half: waveN*64
    const int lr = lane & 15;
    const int lg = lane >> 4;
    const int t0 = blockIdx.x * BM;

    float myc[4];
    #pragma unroll
    for (int nr = 0; nr < 4; ++nr) myc[nr] = csq[waveN * 64 + nr * 16 + lr];

    f32x4 acc[2][4];
    #pragma unroll
    for (int mr = 0; mr < 2; ++mr)
        #pragma unroll
        for (int nr = 0; nr < 4; ++nr)
            acc[mr][nr] = (f32x4){0.f, 0.f, 0.f, 0.f};

    const char* cbsb = (const char*)cbs;

    // A stage: 512 chunks of 16B; LDS linear, global chunk pre-swizzled.
    // B stage: 1024 chunks of 16B; straight linear copy (swizzle baked in).
    // 6 global_load_lds per thread per stage (2 A + 4 B).
    #define STAGE(buf, s) do {                                               \
        _Pragma("unroll")                                                    \
        for (int it = 0; it < 2; ++it) {                                     \
            int o = it * 256 + tid;                                          \
            int t = o >> 3;                                                  \
            int c = o & 7;                                                   \
            lds_load16((char*)As[buf] + o * 16,                              \
                (const char*)(x + (size_t)(t0 + t) * DIM + (s) * 32          \
                              + ((c ^ (t & 7)) << 2)));                      \
        }                                                                    \
        _Pragma("unroll")                                                    \
        for (int it = 0; it < 4; ++it) {                                     \
            int o = it * 256 + tid;                                          \
            lds_load16((char*)Bs[buf] + o * 16,                              \
                       cbsb + (size_t)(s) * 16384 + o * 16);                 \
        }                                                                    \
    } while (0)

    STAGE(0, 0);

    #pragma unroll
    for (int s = 0; s < 8; ++s) {
        const int cur = s & 1;
        // issue next stage, then wait ONLY for the current stage's loads
        // (counted vmcnt: the 6 next-stage loads stay in flight across the
        // barrier — T4; in-order vmcnt retirement makes vmcnt(6) mean
        // "everything older than the newest 6 has landed").
        if (s < 7) {
            STAGE(cur ^ 1, s + 1);
            asm volatile("s_waitcnt vmcnt(6)" ::: "memory");
        } else {
            asm volatile("s_waitcnt vmcnt(0)" ::: "memory");
        }
        __builtin_amdgcn_s_barrier();          // RAW: all waves' stage-s landed
        __builtin_amdgcn_sched_barrier(0);

        // A fragments from LDS + split2 (row = lr, k = lg*8 + j)
        f16x8 ah[2], am[2];
        #pragma unroll
        for (int mr = 0; mr < 2; ++mr) {
            int t = waveM * 32 + mr * 16 + lr;
            const char* ab = (const char*)As[cur] + t * 128;
            float4 v0 = *(const float4*)(ab + ((((lg * 2)    ) ^ (t & 7)) << 4));
            float4 v1 = *(const float4*)(ab + ((((lg * 2) + 1) ^ (t & 7)) << 4));
            float xv[8] = {v0.x, v0.y, v0.z, v0.w, v1.x, v1.y, v1.z, v1.w};
            #pragma unroll
            for (int e = 0; e < 8; ++e) {
                f16_t h, m;
                split2(xv[e], h, m);
                ah[mr][e] = h; am[mr][e] = m;
            }
        }
        // B fragments + MFMA (3 terms: am*bh, ah*bm, ah*bh)
        #pragma unroll
        for (int nr = 0; nr < 4; ++nr) {
            int n = waveN * 64 + nr * 16 + lr;
            const char* bb = (const char*)Bs[cur] + n * 128;
            f16x8 bh = *(const f16x8*)(bb + (((lg    ) ^ (n & 7)) << 4));
            f16x8 bm = *(const f16x8*)(bb + (((4 + lg) ^ (n & 7)) << 4));
            #pragma unroll
            for (int mr = 0; mr < 2; ++mr) {
                f32x4 c4 = acc[mr][nr];
                c4 = __builtin_amdgcn_mfma_f32_16x16x32_f16(am[mr], bh, c4, 0, 0, 0);
                c4 = __builtin_amdgcn_mfma_f32_16x16x32_f16(ah[mr], bm, c4, 0, 0, 0);
                c4 = __builtin_amdgcn_mfma_f32_16x16x32_f16(ah[mr], bh, c4, 0, 0, 0);
                acc[mr][nr] = c4;
            }
        }

        // WAR: next iteration's STAGE overwrites buf[cur^1], which other
        // waves read this iteration; their lgkm waits happened before their
        // MFMAs, so a raw barrier suffices (no vmcnt drain).
        __builtin_amdgcn_sched_barrier(0);
        __builtin_amdgcn_s_barrier();
        __builtin_amdgcn_sched_barrier(0);
    }
    #undef STAGE

    // ---- pass 1: approx argmin (score = csq - 2*dot), per half ----
    // C layout: col(cluster) = lr (+nr*16), row(token) = lg*4 + reg
    #pragma unroll
    for (int mr = 0; mr < 2; ++mr) {
        #pragma unroll
        for (int reg = 0; reg < 4; ++reg) {
            float bv = INFINITY;
            int bi = 0;
            #pragma unroll
            for (int nr = 0; nr < 4; ++nr) {
                float v = fmaf(-2.f, acc[mr][nr][reg], myc[nr]);
                int c = waveN * 64 + nr * 16 + lr;
                if (v < bv) { bv = v; bi = c; }
            }
            #pragma unroll
            for (int msk = 1; msk < 16; msk <<= 1) {
                float ov = __shfl_xor(bv, msk, 64);
                int oi = __shfl_xor(bi, msk, 64);
                if (ov < bv || (ov == bv && oi < bi)) { bv = ov; bi = oi; }
            }
            if (lr == 0) {
                int t = waveM * 32 + mr * 16 + lg * 4 + reg;
                sminv[waveN][t] = bv;
                smini[waveN][t] = bi;
            }
        }
    }
    __syncthreads();
    if (tid < BM) {
        float v0 = sminv[0][tid], v1 = sminv[1][tid];
        sminT[tid] = fminf(v0, v1);
        sbest[tid] = (v1 < v0) ? smini[1][tid] : smini[0][tid];
        scnt[tid] = 0;
    }
    __syncthreads();

    // ---- pass 2: count candidates within EPS of the min ----
    #pragma unroll
    for (int mr = 0; mr < 2; ++mr) {
        #pragma unroll
        for (int reg = 0; reg < 4; ++reg) {
            int t = waveM * 32 + mr * 16 + lg * 4 + reg;
            float thr = sminT[t] + EPS;
            int cnt = 0;
            #pragma unroll
            for (int nr = 0; nr < 4; ++nr) {
                float v = fmaf(-2.f, acc[mr][nr][reg], myc[nr]);
                cnt += (v <= thr) ? 1 : 0;
            }
            if (cnt > 0) atomicAdd(&scnt[t], cnt);
        }
    }
    __syncthreads();

    // ---- pass 3: exact fp32 recheck for near-tie tokens (rare) ----
    // Bitwise round-1 arithmetic: sequential-k fmaf dot & xsq,
    // d2 = fmaf(-2,dot,xsq) + csq, lexicographic (value,idx) min.
    for (int tt = 0; tt < 16; ++tt) {
        int t = wid * 16 + tt;
        if (scnt[t] < 2) continue;   // wave-uniform
        const float4* xr = (const float4*)(x + (size_t)(t0 + t) * DIM);
        const float4* c0 = (const float4*)(centers + (size_t)(2 * lane) * DIM);
        const float4* c1 = (const float4*)(centers + (size_t)(2 * lane + 1) * DIM);
        float xs = 0.f, d0 = 0.f, d1 = 0.f;
        #pragma unroll 4
        for (int k4 = 0; k4 < 64; ++k4) {
            float4 xv = xr[k4];
            float4 a = c0[k4];
            float4 b = c1[k4];
            xs = fmaf(xv.x, xv.x, xs); d0 = fmaf(xv.x, a.x, d0); d1 = fmaf(xv.x, b.x, d1);
            xs = fmaf(xv.y, xv.y, xs); d0 = fmaf(xv.y, a.y, d0); d1 = fmaf(xv.y, b.y, d1);
            xs = fmaf(xv.z, xv.z, xs); d0 = fmaf(xv.z, a.z, d0); d1 = fmaf(xv.z, b.z, d1);
            xs = fmaf(xv.w, xv.w, xs); d0 = fmaf(xv.w, a.w, d0); d1 = fmaf(xv.w, b.w, d1);
        }
        float s0 = fmaf(-2.f, d0, xs) + csq[2 * lane];
        float s1 = fmaf(-2.f, d1, xs) + csq[2 * lane + 1];
        float bv = s0;
        int bi = 2 * lane;
        if (s1 < bv) { bv = s1; bi = 2 * lane + 1; }
        #pragma unroll
        for (int msk = 1; msk < 64; msk <<= 1) {
            float ov = __shfl_xor(bv, msk, 64);
            int oi = __shfl_xor(bi, msk, 64);
            if (ov < bv || (ov == bv && oi < bi)) { bv = ov; bi = oi; }
        }
        if (lane == 0) sbest[t] = bi;
    }
    __syncthreads();

    // ---- epilogue: out[t][:] = pc[best[t]][:] * keep ----
    #pragma unroll
    for (int it = 0; it < 16; ++it) {
        int idx = it * 256 + tid;
        int t = idx >> 6;
        int f4 = idx & 63;
        int best = sbest[t];
        float mval = masks[t0 + t] ? 0.f : 1.f;
        float4 v = *(const float4*)(pc + (size_t)best * DOUT + f4 * 4);
        v.x *= mval; v.y *= mval; v.z *= mval; v.w *= mval;
        *(float4*)(out + (size_t)(t0 + t) * DOUT + f4 * 4) = v;
    }
}

extern "C" void kernel_launch(void* const* d_in, const int* in_sizes, int n_in,
                              void* d_out, int out_size, void* d_ws, size_t ws_size,
                              hipStream_t stream) {
    const float* x = (const float*)d_in[0];
    const float* centers = (const float*)d_in[1];
    const float* proj_w = (const float*)d_in[2];
    const float* proj_b = (const float*)d_in[3];
    const unsigned char* masks = (const unsigned char*)d_in[4];
    float* out = (float*)d_out;

    char* ws = (char*)d_ws;
    float* pc   = (float*)(ws);                 // 131072 B
    float* csq  = (float*)(ws + 131072);        // 512 B
    f16_t* cbs  = (f16_t*)(ws + 131584);        // 128*512*2 = 131072 B

    precompute_kernel<<<NCLUST, 256, 0, stream>>>(centers, proj_w, proj_b,
                                                  pc, csq, cbs);
    cluster_mfma_kernel<<<N_TOKENS / BM, 256, 0, stream>>>(x, centers, cbs,
                                                           csq, pc, masks, out);
}